// Round 12
// baseline (97.608 us; speedup 1.0000x reference)
//
#include <hip/hip_runtime.h>
#include <math.h>

// Capsule dynamic routing v13 — v10's winning shape + 8-lane W-dedup + max waves.
// Synthesis of R8-R11: perf tracks (occupancy x per-wave MLP); dedup only pays
// once latency is hidden. v13 = T=1024 (16 waves, 2 blocks fill a CU), 8-lane
// groups (lanes 0-3: batch b0, 4-7: b1 -> same W addresses, coalescer merges,
// L1 W-bytes halve), NGROUP=128 so RPT=9 (v10's proven depth), v10 1-row
// lookahead, v9 fused routing (no max pass, Z folded, 1 reduction round).
// Per-thread state identical to v10 (~60 VGPR, proven no-spill).
//
// x: [B=256, R=1152, I=8] f32
// W: [C=10, R=1152, I=8, O=16] f32
// out: [B=256, C=10, O=16] f32
//
// One block per (c, b-pair). 1024 threads = 128 groups of 8 lanes; 16 waves.
// Group g owns rows r = g + j*128 (j=0..8); lane q=t&3 owns o-quad,
// bsel=(t>>2)&1 selects the batch.

#define C_CAPS 10
#define B_SZ   256
#define R_SZ   1152
#define I_SZ   8
#define O_SZ   16
#define G_B    2         // batches per block (via lane split)
#define T_THREADS 1024
#define NGROUP 128       // T/8 groups
#define RPT 9            // rows per group = R / NGROUP
#define NW 16            // waves per block

__global__ __launch_bounds__(T_THREADS, 1) void capsule_kernel(
    const float* __restrict__ x,
    const float* __restrict__ w,
    float* __restrict__ out)
{
    const int c  = blockIdx.x >> 7;        // / (B/G)
    const int bb = blockIdx.x & 127;       // % (B/G)
    const int b0 = bb * G_B;
    const int t = (int)threadIdx.x;
    const int lane = t & 63;
    const int wid = t >> 6;
    const int q    = t & 3;                // o-quad index
    const int bsel = (t >> 2) & 1;         // which batch this lane serves
    const int g    = t >> 3;               // group id 0..127

    __shared__ float4 red_s[NW][G_B][4];   // per-wave s-partials
    __shared__ float  red_z[NW][G_B];      // per-wave Z-partials
    __shared__ float4 s_fin[G_B][4];       // combined s per (bsel,q)
    __shared__ float  z_fin[G_B];          // combined Z per bsel

    // ---- priors with 1-row lookahead: P[j][k], rows r = g + j*128 ----
    float P[RPT][4];

    const float* xbase = x + ((size_t)(b0 + bsel) * R_SZ + g) * I_SZ;
    // lanes q and q+4 share the same W address -> one L1 line serves both
    const float* wbase = w + ((size_t)c * R_SZ + g) * (I_SZ * O_SZ) + q * 4;
    const size_t xstep = (size_t)NGROUP * I_SZ;
    const size_t wstep = (size_t)NGROUP * I_SZ * O_SZ;

    // preload row j=0
    float4 xc0 = *(const float4*)(xbase);
    float4 xc1 = *(const float4*)(xbase + 4);
    float4 wc[8];
    #pragma unroll
    for (int i = 0; i < I_SZ; ++i) wc[i] = *(const float4*)(wbase + i * O_SZ);

    #pragma unroll
    for (int j = 0; j < RPT; ++j) {
        float4 xn0, xn1, wn[8];
        if (j < RPT - 1) {
            const float* xp = xbase + (j + 1) * xstep;
            const float* wp = wbase + (j + 1) * wstep;
            xn0 = *(const float4*)(xp);
            xn1 = *(const float4*)(xp + 4);
            #pragma unroll
            for (int i = 0; i < I_SZ; ++i) wn[i] = *(const float4*)(wp + i * O_SZ);
        }
        const float xi[I_SZ] = {xc0.x, xc0.y, xc0.z, xc0.w,
                                xc1.x, xc1.y, xc1.z, xc1.w};
        float a0 = 0.f, a1 = 0.f, a2 = 0.f, a3 = 0.f;
        #pragma unroll
        for (int i = 0; i < I_SZ; ++i) {
            a0 = fmaf(xi[i], wc[i].x, a0);
            a1 = fmaf(xi[i], wc[i].y, a1);
            a2 = fmaf(xi[i], wc[i].z, a2);
            a3 = fmaf(xi[i], wc[i].w, a3);
        }
        P[j][0] = a0; P[j][1] = a1; P[j][2] = a2; P[j][3] = a3;
        if (j < RPT - 1) {
            xc0 = xn0; xc1 = xn1;
            #pragma unroll
            for (int i = 0; i < I_SZ; ++i) wc[i] = wn[i];
        }
    }

    float logit[RPT];
    #pragma unroll
    for (int j = 0; j < RPT; ++j) logit[j] = 0.0f;

    float vq[4];   // this lane's o-quad of its batch's squashed output

    for (int it = 0; it < 3; ++it) {
        // ---- fused exp + weighted-sum partials (no max pass; |logit|<=~40
        //      keeps exp and Z inside f32 range) ----
        float sa0 = 0.f, sa1 = 0.f, sa2 = 0.f, sa3 = 0.f, zp = 0.f;
        #pragma unroll
        for (int j = 0; j < RPT; ++j) {
            const float e = __expf(logit[j]);   // it==0: exp(0)=1 exactly
            zp += e;
            sa0 = fmaf(e, P[j][0], sa0);
            sa1 = fmaf(e, P[j][1], sa1);
            sa2 = fmaf(e, P[j][2], sa2);
            sa3 = fmaf(e, P[j][3], sa3);
        }
        // reduce across the wave's 8 groups (lanes with equal t&7): 3 steps
        #pragma unroll
        for (int m = 8; m <= 32; m <<= 1) {
            sa0 += __shfl_xor(sa0, m, 64);
            sa1 += __shfl_xor(sa1, m, 64);
            sa2 += __shfl_xor(sa2, m, 64);
            sa3 += __shfl_xor(sa3, m, 64);
            zp  += __shfl_xor(zp,  m, 64);
        }
        if (lane < 8) {
            red_s[wid][lane >> 2][lane & 3] = make_float4(sa0, sa1, sa2, sa3);
            if ((lane & 3) == 0) red_z[wid][lane >> 2] = zp;
        }
        __syncthreads();

        // ---- one-wave combine (threads 0..9), then broadcast ----
        if (t < G_B * 4) {                       // t=0..7: bsel=t>>2, q=t&3
            float4 a = red_s[0][t >> 2][t & 3];
            #pragma unroll
            for (int ww = 1; ww < NW; ++ww) {
                const float4 rr = red_s[ww][t >> 2][t & 3];
                a.x += rr.x; a.y += rr.y; a.z += rr.z; a.w += rr.w;
            }
            s_fin[t >> 2][t & 3] = a;
        }
        if (t >= 8 && t < 8 + G_B) {             // t=8,9: bsel=t-8
            float zz = red_z[0][t - 8];
            #pragma unroll
            for (int ww = 1; ww < NW; ++ww) zz += red_z[ww][t - 8];
            z_fin[t - 8] = zz;
        }
        __syncthreads();

        // ---- normalize + squash (normalize BEFORE squaring: overflow-safe) ----
        const float invZ = 1.0f / z_fin[bsel];
        const float4 sf = s_fin[bsel][q];
        const float u0 = sf.x * invZ, u1 = sf.y * invZ,
                    u2 = sf.z * invZ, u3 = sf.w * invZ;
        float nq = u0*u0 + u1*u1 + u2*u2 + u3*u3;
        nq += __shfl_xor(nq, 1, 64);             // masks 1,2 stay within bsel
        nq += __shfl_xor(nq, 2, 64);
        const float scale = nq / ((1.0f + nq) * sqrtf(nq));
        vq[0] = scale * u0; vq[1] = scale * u1;
        vq[2] = scale * u2; vq[3] = scale * u3;

        // ---- logit update (iters 0,1): logit[r] += P[r]·v ----
        if (it < 2) {
            #pragma unroll
            for (int j = 0; j < RPT; ++j) {
                float d = P[j][0]*vq[0] + P[j][1]*vq[1]
                        + P[j][2]*vq[2] + P[j][3]*vq[3];
                d += __shfl_xor(d, 1, 64);
                d += __shfl_xor(d, 2, 64);
                logit[j] += d;
            }
        }
        // no end-of-iter barrier: red_s(it+1) writes occur only after
        // barrier #2(it) releases; s_fin(it+1) writes only after
        // barrier #1(it+1). Same proof as v9/v12.
    }

    // ---- write out[b0+bsel, c, :]: threads 0..7 hold (bsel, quad) ----
    if (t < 8) {
        float* op = out + ((size_t)(b0 + (t >> 2)) * C_CAPS + c) * O_SZ + (t & 3) * 4;
        *(float4*)op = make_float4(vq[0], vq[1], vq[2], vq[3]);
    }
}

extern "C" void kernel_launch(void* const* d_in, const int* in_sizes, int n_in,
                              void* d_out, int out_size, void* d_ws, size_t ws_size,
                              hipStream_t stream) {
    const float* x = (const float*)d_in[0];
    const float* w = (const float*)d_in[1];
    float* out = (float*)d_out;
    dim3 grid(C_CAPS * (B_SZ / G_B));
    dim3 block(T_THREADS);
    hipLaunchKernelGGL(capsule_kernel, grid, block, 0, stream, x, w, out);
}